// Round 3
// baseline (463.858 us; speedup 1.0000x reference)
//
#include <hip/hip_runtime.h>

// Problem constants (from reference): x is (B=16, C4=256, H=128, W=128) f32,
// out is (B=16, C=64, 2H=256, 2W=256) f32.
// out[b,c,2i+0,2j+0] = 0.5*(a - bb - cc + d)   (h00)
// out[b,c,2i+0,2j+1] = 0.5*(a + bb - cc - d)   (h01)
// out[b,c,2i+1,2j+0] = 0.5*(a - bb + cc - d)   (h10)
// out[b,c,2i+1,2j+1] = 0.5*(a + bb + cc + d)   (h11)
// where a=x[b,c], bb=x[b,c+64], cc=x[b,c+128], d=x[b,c+192].
//
// Pure streaming (zero reuse): nontemporal loads/stores so L2/L3 don't
// retain dead lines (537 MB total traffic >> 256 MiB L3).
// NOTE: nontemporal builtins require native clang vector types, not
// HIP_vector_type (float4) — use ext_vector_type(4) float.

#define IWT_B 16
#define IWT_C 64
#define IWT_H 128
#define IWT_W 128

typedef float f32x4 __attribute__((ext_vector_type(4)));

__global__ __launch_bounds__(256) void IWT_kernel(const float* __restrict__ x,
                                                  float* __restrict__ out) {
    // One thread per (b, c, i, jv) with jv indexing a 4-wide column chunk.
    const unsigned tid = blockIdx.x * 256u + threadIdx.x;
    const int jv = tid & 31;          // W/4 - 1
    const int i  = (tid >> 5) & 127;  // H - 1
    const int c  = (tid >> 12) & 63;  // C - 1
    const int b  = tid >> 18;

    const long long chanStride = (long long)IWT_H * IWT_W;  // 16384
    const long long inBase =
        (((long long)b * 256 + c) * IWT_H + i) * IWT_W + (jv << 2);

    const f32x4 a  = __builtin_nontemporal_load((const f32x4*)(x + inBase));
    const f32x4 bb = __builtin_nontemporal_load((const f32x4*)(x + inBase + 64  * chanStride));
    const f32x4 cc = __builtin_nontemporal_load((const f32x4*)(x + inBase + 128 * chanStride));
    const f32x4 d  = __builtin_nontemporal_load((const f32x4*)(x + inBase + 192 * chanStride));

    f32x4 h00, h01, h10, h11;
    h00 = 0.5f * (a - bb - cc + d);
    h01 = 0.5f * (a + bb - cc - d);
    h10 = 0.5f * (a - bb + cc - d);
    h11 = 0.5f * (a + bb + cc + d);

    // Output: (B, 64, 256, 256). Rows 2i and 2i+1, cols 8*jv .. 8*jv+7.
    const long long outRow0 =
        (((long long)b * IWT_C + c) * (2 * IWT_H) + 2 * i) * (2 * IWT_W) + (jv << 3);
    const long long outRow1 = outRow0 + 2 * IWT_W;

    f32x4 r0a = {h00.x, h01.x, h00.y, h01.y};
    f32x4 r0b = {h00.z, h01.z, h00.w, h01.w};
    f32x4 r1a = {h10.x, h11.x, h10.y, h11.y};
    f32x4 r1b = {h10.z, h11.z, h10.w, h11.w};

    __builtin_nontemporal_store(r0a, (f32x4*)(out + outRow0));
    __builtin_nontemporal_store(r0b, (f32x4*)(out + outRow0 + 4));
    __builtin_nontemporal_store(r1a, (f32x4*)(out + outRow1));
    __builtin_nontemporal_store(r1b, (f32x4*)(out + outRow1 + 4));
}

extern "C" void kernel_launch(void* const* d_in, const int* in_sizes, int n_in,
                              void* d_out, int out_size, void* d_ws, size_t ws_size,
                              hipStream_t stream) {
    const float* x = (const float*)d_in[0];
    float* out = (float*)d_out;
    IWT_kernel<<<16384, 256, 0, stream>>>(x, out);
}

// Round 4
// 425.645 us; speedup vs baseline: 1.0898x; 1.0898x over previous
//
#include <hip/hip_runtime.h>

// x: (B=16, C4=256, H=128, W=128) f32 -> out: (16, 64, 256, 256) f32.
// out[b,c,2i,2j+0]=0.5(a-bb-cc+d)  out[b,c,2i,2j+1]=0.5(a+bb-cc-d)
// out[b,c,2i+1,2j]=0.5(a-bb+cc-d)  out[b,c,2i+1,2j+1]=0.5(a+bb+cc+d)
// a=x[b,c], bb=x[b,c+64], cc=x[b,c+128], d=x[b,c+192].
//
// Mapping: thread = (b,c,i,q), q in [0,64). Loads 2 floats (8 B) per channel
// at columns 2q,2q+1; writes 4 floats (16 B) to output row 2i and 16 B to row
// 2i+1. A wave (64 lanes, one full i-row) issues:
//   4x global_load_dwordx2  -> dense 512 B each (every input byte read once)
//   2x global_store_dwordx4 -> dense 1024 B each = exactly one output row
// Fully dense per-instruction stores (previous version was 50%-dense,
// 16 B/lane at 32 B stride). No NT hints (round-3 evidence: NT cost +35 us).

typedef float f32x2 __attribute__((ext_vector_type(2)));
typedef float f32x4 __attribute__((ext_vector_type(4)));

__global__ __launch_bounds__(256) void IWT_kernel(const float* __restrict__ x,
                                                  float* __restrict__ out) {
    const unsigned tid = blockIdx.x * 256u + threadIdx.x;
    // total threads = B*C*H*(W/2) = 16*64*128*64 = 8388608 -> 32768 blocks
    const int q = tid & 63;           // column pair index, 2q in [0,128)
    const int i = (tid >> 6) & 127;   // input row
    const int c = (tid >> 13) & 63;   // output channel
    const int b = tid >> 19;          // batch

    const long long chanStride = 128LL * 128;  // 16384
    const long long inBase =
        (((long long)b * 256 + c) * 128 + i) * 128 + (q << 1);

    const f32x2 a  = *(const f32x2*)(x + inBase);
    const f32x2 bb = *(const f32x2*)(x + inBase + 64  * chanStride);
    const f32x2 cc = *(const f32x2*)(x + inBase + 128 * chanStride);
    const f32x2 d  = *(const f32x2*)(x + inBase + 192 * chanStride);

    const f32x2 h00 = 0.5f * (a - bb - cc + d);
    const f32x2 h01 = 0.5f * (a + bb - cc - d);
    const f32x2 h10 = 0.5f * (a - bb + cc - d);
    const f32x2 h11 = 0.5f * (a + bb + cc + d);

    // out row 2i: [h00[0],h01[0],h00[1],h01[1]] at cols 4q..4q+3
    // out row 2i+1: [h10[0],h11[0],h10[1],h11[1]]
    const long long outRow0 =
        (((long long)b * 64 + c) * 256 + 2 * i) * 256 + (q << 2);

    const f32x4 r0 = {h00.x, h01.x, h00.y, h01.y};
    const f32x4 r1 = {h10.x, h11.x, h10.y, h11.y};

    *(f32x4*)(out + outRow0)       = r0;
    *(f32x4*)(out + outRow0 + 256) = r1;
}

extern "C" void kernel_launch(void* const* d_in, const int* in_sizes, int n_in,
                              void* d_out, int out_size, void* d_ws, size_t ws_size,
                              hipStream_t stream) {
    const float* x = (const float*)d_in[0];
    float* out = (float*)d_out;
    IWT_kernel<<<32768, 256, 0, stream>>>(x, out);
}